// Round 11
// baseline (869.255 us; speedup 1.0000x reference)
//
#include <hip/hip_runtime.h>

#define HDIM 1024
#define TILE 32
#define HALO 20            // 2*PAD
#define MID  52            // TILE + HALO
#define ABW  1044          // (a,b) grid extent per side
#define ABP2 1056          // (a,b) plane row pitch in float2
#define EPSF 1e-8f
#define INVF ((float)(1.0 / 441.0))

// window-21 min/max scan: o[t] = (min,max) over v[t..t+20], t in [0,8), inputs v[0..27]
__device__ __forceinline__ void scan8_mm(const float* vm, const float* vx, float2* o) {
    float smn[8], smx[8];
    float amn = vm[20], amx = vx[20];
#pragma unroll
    for (int j = 19; j >= 8; --j) { amn = fminf(amn, vm[j]); amx = fmaxf(amx, vx[j]); }
#pragma unroll
    for (int i = 7; i >= 0; --i) {
        amn = fminf(amn, vm[i]); amx = fmaxf(amx, vx[i]);
        smn[i] = amn; smx[i] = amx;
    }
    float pmn = vm[21], pmx = vx[21];
    o[0] = make_float2(smn[0], smx[0]);
#pragma unroll
    for (int i = 1; i < 8; ++i) {
        o[i] = make_float2(fminf(smn[i], pmn), fmaxf(smx[i], pmx));
        if (i < 7) { pmn = fminf(pmn, vm[21 + i]); pmx = fmaxf(pmx, vx[21 + i]); }
    }
}

// ======================= K1: img -> (a,b) plane, 32x32 tiles, 2 phases =======================
// Phase 1: h-minmax streamed from GLOBAL (no img staging), lane-scatter transposed into LDS.
// Phase 2: v-minmax + (a,b) + store.  LDS: hmmT [32 cols][108 w] = 3456 w = 13.8 KB.
#define K1_PITCH 108
#define K1_WORDS 3456

__global__ __launch_bounds__(256, 7) void san_k1(const float* __restrict__ img,
                                                 float2* __restrict__ ab) {
    __shared__ __align__(16) float smem[K1_WORDS];
    const int tid = threadIdx.x;
    const int I0 = blockIdx.x * TILE;
    const int J0 = blockIdx.y * TILE;
    const float* __restrict__ imc = img + (size_t)blockIdx.z * (HDIM * HDIM);
    float2* __restrict__ abc = ab + (size_t)blockIdx.z * ((size_t)ABW * ABP2);
    // interior in x: all loads base>=0 and base+27<=1023
    const bool xInt = (I0 >= 32) && (I0 <= HDIM - 32);

    // ---- phase 1: h-minmax. 52 rows x 4 groups of 8 = 208 lanes.
    //      output x = 8g+t needs cols I0+x-20..I0+x -> lane reads 28 cols from base = I0+8g-20 ----
    if (tid < 208) {
        int r = tid >> 2, g = tid & 3;
        int gy = min(HDIM - 1, max(0, J0 - HALO + r));
        const float* rowp = imc + (size_t)gy * HDIM;
        int base = I0 + 8 * g - HALO;          // even
        float v[28];
        if (xInt) {
            const float2* p2 = (const float2*)(rowp + base);
#pragma unroll
            for (int k = 0; k < 14; ++k) { float2 t = p2[k]; v[2 * k] = t.x; v[2 * k + 1] = t.y; }
        } else {
#pragma unroll
            for (int k = 0; k < 28; ++k) v[k] = rowp[min(HDIM - 1, max(0, base + k))];
        }
        float2 o[8];
        scan8_mm(v, v, o);
#pragma unroll
        for (int t = 0; t < 8; ++t)
            *(float2*)&smem[(8 * g + t) * K1_PITCH + 2 * r] = o[t];   // transposed scatter
    }
    __syncthreads();

    // ---- phase 2: v-minmax + (a,b) + store. 32 cols x 4 groups of 8 = 128 lanes ----
    if (tid < 128) {
        int i = tid & 31, gj = tid >> 5;
        const float4* p4 = (const float4*)&smem[i * K1_PITCH + 16 * gj];
        float vm[28], vx[28];
#pragma unroll
        for (int k = 0; k < 14; ++k) {
            float4 q = p4[k];
            vm[2 * k] = q.x; vx[2 * k] = q.y; vm[2 * k + 1] = q.z; vx[2 * k + 1] = q.w;
        }
        float2 o[8];
        scan8_mm(vm, vx, o);
#pragma unroll
        for (int t = 0; t < 8; ++t) {
            int jj = J0 + 8 * gj + t, ii = I0 + i;
            float mn = o[t].x, d = o[t].y - o[t].x;
            float a, b;
            if (d == 0.0f) {      // degenerate corner Q-point: clamp (consumer fixed up in K2)
                a = 1.0f; b = 0.0f;
            } else {
                a = 1.0f / (d + EPSF);
                b = mn * a;
            }
            if (jj < ABW && ii < ABW)
                abc[(size_t)jj * ABP2 + ii] = make_float2(a, b);
        }
    }
}

// ======================= K2: box-filter + combine, 32x32 tiles, 2 phases =======================
// Phase 1: h-sums streamed from GLOBAL ab (no staging), lane-scatter transposed into LDS;
//          corner blocks: lanes 208..255 preload the 21x21 ab fix patch into fixbuf.
// Phase 2: v-sums + combine + store; corner pixel's owner lane substitutes the bit-exact fixVal.
// LDS: hsT [32 cols][108 w] = 3456 + fixbuf 882 = 4338 w -> 17.4 KB.
#define K2_PITCH 108
#define K2_FIXOFF 3456
#define K2_WORDS 4344

__global__ __launch_bounds__(256, 7) void san_k2(const float* __restrict__ img,
                                                 const float2* __restrict__ ab,
                                                 float* __restrict__ out) {
    __shared__ __align__(16) float smem[K2_WORDS];
    const int tid = threadIdx.x;
    const int I0 = blockIdx.x * TILE;
    const int J0 = blockIdx.y * TILE;
    const float* __restrict__ imc = img + (size_t)blockIdx.z * (HDIM * HDIM);
    const float2* __restrict__ abc = ab + (size_t)blockIdx.z * ((size_t)ABW * ABP2);
    float* __restrict__ oc = out + (size_t)blockIdx.z * (HDIM * HDIM);

    const bool cornerBlk = (blockIdx.x == 0 || blockIdx.x == gridDim.x - 1) &&
                           (blockIdx.y == 0 || blockIdx.y == gridDim.y - 1);
    const int fixPy = (blockIdx.y == 0) ? 0 : (TILE - 1);
    const int fixPx = (blockIdx.x == 0) ? 0 : (TILE - 1);

    // ---- prefetch this thread's 4 output pixels (used in phase 2) ----
    const int px_x = I0 + (tid & 31);
    const int px_y0 = J0 + 4 * (tid >> 5);
    float pix[4];
#pragma unroll
    for (int t = 0; t < 4; ++t) pix[t] = imc[(px_y0 + t) * HDIM + px_x];

    // ---- phase 1: h sliding sums from global. 52 rows x 4 groups of 8 = 208 lanes ----
    if (tid < 208) {
        int v = tid >> 2, g = tid & 3;
        const float4* p4 = (const float4*)(abc + (size_t)(J0 + v) * ABP2 + I0 + 8 * g);
        float2 lo[7], hi[7];          // abv[0..6] and abv[21..27]; middle consumed on the fly
        float Sa = 0.0f, Sb = 0.0f;
#pragma unroll
        for (int k = 0; k < 14; ++k) {
            float4 q = p4[k];
            float2 e0 = make_float2(q.x, q.y);   // abv[2k]
            float2 e1 = make_float2(q.z, q.w);   // abv[2k+1]
            int i0 = 2 * k, i1 = 2 * k + 1;
            if (i0 < 7)  lo[i0] = e0;
            if (i1 < 7)  lo[i1] = e1;
            if (i0 >= 21) hi[i0 - 21] = e0;
            if (i1 >= 21) hi[i1 - 21] = e1;
            if (i0 < 21) { Sa += e0.x; Sb += e0.y; }
            if (i1 < 21) { Sa += e1.x; Sb += e1.y; }
        }
        float hsa[8], hsb[8];
        hsa[0] = Sa; hsb[0] = Sb;
#pragma unroll
        for (int t = 1; t < 8; ++t) {
            Sa += hi[t - 1].x - lo[t - 1].x;     // abv[t+20] - abv[t-1]
            Sb += hi[t - 1].y - lo[t - 1].y;
            hsa[t] = Sa; hsb[t] = Sb;
        }
#pragma unroll
        for (int t = 0; t < 8; ++t)
            *(float2*)&smem[(8 * g + t) * K2_PITCH + 2 * v] = make_float2(hsa[t], hsb[t]);
    } else if (cornerBlk) {
        // lanes 208..255 (48 lanes): preload the 21x21 ab patch for the corner fixup.
        // (stride MUST equal the participating lane count: 48, not 64 — R10 bug)
        int l = tid - 208;
        for (int idx = l; idx < 441; idx += 48) {
            int dy = idx / 21, dx = idx - 21 * dy;
            float2 t = abc[(size_t)(J0 + fixPy + dy) * ABP2 + (I0 + fixPx + dx)];
            *(float2*)&smem[K2_FIXOFF + 2 * idx] = t;
        }
    }
    __syncthreads();

    // ---- phase 2: v sliding sums + combine + store. 32 cols x 8 groups of 4 = 256 lanes ----
    {
        int x = tid & 31, h = tid >> 5;
        const float4* p4 = (const float4*)&smem[x * K2_PITCH + 8 * h];
        float2 vv[24];
#pragma unroll
        for (int k = 0; k < 12; ++k) {
            float4 q = p4[k];
            vv[2 * k]     = make_float2(q.x, q.y);
            vv[2 * k + 1] = make_float2(q.z, q.w);
        }
        float Sa = 0.0f, Sb = 0.0f;
#pragma unroll
        for (int j = 0; j < 21; ++j) { Sa += vv[j].x; Sb += vv[j].y; }

        // corner fixup: bit-exact f32 replica of reference row-major sequential sums,
        // computed by the corner pixel's OWNER lane (no second writer).
        const bool haveFix = cornerBlk && (x == fixPx) && (h == (fixPy >> 2));
        float fv = 0.0f;
        if (haveFix) {
            int degY = (blockIdx.y == 0) ? 0 : HALO;   // window-relative pos of degenerate Q
            int degX = (blockIdx.x == 0) ? 0 : HALO;
            float pv = pix[fixPy & 3];
            float aT = 1.0f / EPSF;          // true a at degenerate point
            float bT = pv * aT;              // true b (single rounded f32 mul)
            asm volatile("" : "+v"(bT));     // forbid fma contraction
            float Fa = 0.0f, Fb = 0.0f;
#pragma unroll 1
            for (int dy = 0; dy < 21; ++dy) {
#pragma unroll 1
                for (int dx = 0; dx < 21; ++dx) {
                    const float* c = &smem[K2_FIXOFF + 2 * (dy * 21 + dx)];
                    float av = c[0], bv = c[1];
                    if (dy == degY && dx == degX) { av = aT; bv = bT; }
                    Fa = Fa + av;
                    Fb = Fb + bv;
                }
            }
            float avga = Fa * INVF;
            float avgb = Fb * INVF;
            float tq = pv * avga;
            asm volatile("" : "+v"(tq));     // mul then sub, like materialized ref
            fv = tq - avgb;
        }

#pragma unroll
        for (int t = 0; t < 4; ++t) {
            if (t > 0) {
                Sa += vv[t + 20].x - vv[t - 1].x;
                Sb += vv[t + 20].y - vv[t - 1].y;
            }
            float avga = Sa * INVF, avgb = Sb * INVF;
            float val = pix[t] * avga - avgb;
            if (haveFix && t == (fixPy & 3)) val = fv;
            oc[(px_y0 + t) * HDIM + px_x] = val;
        }
    }
}

// ======================= fused fallback (R4, proven) =======================
#define IMG_PITCH 74
#define REG2 5616
#define HMM_STRIDE 148
#define AB_PITCH 108
#define HS_STRIDE 106
#define SMEM_WORDS 13328

__device__ __forceinline__ void scan14_mm(const float* vm, const float* vx, float2* o) {
    float smn[14], smx[14];
    float amn = vm[20], amx = vx[20];
#pragma unroll
    for (int j = 19; j >= 14; --j) { amn = fminf(amn, vm[j]); amx = fmaxf(amx, vx[j]); }
#pragma unroll
    for (int i = 13; i >= 0; --i) {
        amn = fminf(amn, vm[i]); amx = fmaxf(amx, vx[i]);
        smn[i] = amn; smx[i] = amx;
    }
    float pmn = vm[21], pmx = vx[21];
    o[0] = make_float2(smn[0], smx[0]);
#pragma unroll
    for (int i = 1; i < 14; ++i) {
        o[i] = make_float2(fminf(smn[i], pmn), fmaxf(smx[i], pmx));
        if (i < 13) { pmn = fminf(pmn, vm[21 + i]); pmx = fmaxf(pmx, vx[21 + i]); }
    }
}

__global__ __launch_bounds__(256, 3) void san_fused(const float* __restrict__ img,
                                                    float* __restrict__ out) {
    __shared__ __align__(16) float smem[SMEM_WORDS];
    const int tid = threadIdx.x;
    const int ox0 = blockIdx.x * TILE;
    const int oy0 = blockIdx.y * TILE;
    const float* __restrict__ imc = img + (size_t)blockIdx.z * (HDIM * HDIM);
    float* __restrict__ oc = out + (size_t)blockIdx.z * (HDIM * HDIM);
    const bool xInterior = (blockIdx.x > 0) && (blockIdx.x < gridDim.x - 1);

    for (int idx = tid; idx < 72 * 36; idx += 256) {
        int r = idx / 36, c2 = idx - r * 36;
        int gy = min(HDIM - 1, max(0, oy0 - HALO + r));
        float2 t;
        if (xInterior) {
            t = *(const float2*)(imc + gy * HDIM + (ox0 - HALO) + 2 * c2);
        } else {
            int gx0 = min(HDIM - 1, max(0, ox0 - HALO + 2 * c2));
            int gx1 = min(HDIM - 1, max(0, ox0 - HALO + 2 * c2 + 1));
            t = make_float2(imc[gy * HDIM + gx0], imc[gy * HDIM + gx1]);
        }
        *(float2*)&smem[r * IMG_PITCH + 2 * c2] = t;
    }
    __syncthreads();

    for (int task = tid; task < 288; task += 256) {
        int r = task >> 2, g = task & 3, u0 = 14 * g;
        const float2* p = (const float2*)&smem[r * IMG_PITCH + u0];
        float v[34];
#pragma unroll
        for (int k = 0; k < 17; ++k) { float2 t = p[k]; v[2 * k] = t.x; v[2 * k + 1] = t.y; }
        float2 o[14];
        scan14_mm(v, v, o);
#pragma unroll
        for (int i = 0; i < 14; ++i) {
            int u = u0 + i;
            if (u < MID) *(float2*)&smem[REG2 + u * HMM_STRIDE + 2 * r] = o[i];
        }
    }
    __syncthreads();

    if (tid < 208) {
        int u = tid % MID, v0 = 14 * (tid / MID);
        const float4* p = (const float4*)&smem[REG2 + u * HMM_STRIDE + 2 * v0];
        float vm[34], vx[34];
#pragma unroll
        for (int k = 0; k < 17; ++k) {
            float4 q = p[k];
            vm[2 * k] = q.x; vx[2 * k] = q.y; vm[2 * k + 1] = q.z; vx[2 * k + 1] = q.w;
        }
        float2 o[14];
        scan14_mm(vm, vx, o);
#pragma unroll
        for (int i = 0; i < 14; ++i) {
            int v = v0 + i;
            if (v < MID) {
                float mn = o[i].x, d = o[i].y - o[i].x;
                float a, b;
                if (d == 0.0f) { a = 1.0f; b = 0.0f; }
                else { a = 1.0f / (d + EPSF); b = mn * a; }
                *(float2*)&smem[v * AB_PITCH + 2 * u] = make_float2(a, b);
            }
        }
    }
    __syncthreads();

    const bool cornerBlk = (blockIdx.x == 0 || blockIdx.x == gridDim.x - 1) &&
                           (blockIdx.y == 0 || blockIdx.y == gridDim.y - 1);
    float fixVal = 0.0f;
    int fixPy = 0, fixPx = 0;
    if (tid < 208) {
        int v = tid >> 2, g = tid & 3, xb = 8 * g;
        const float4* p = (const float4*)&smem[v * AB_PITCH + 16 * g];
        float2 ab[28];
#pragma unroll
        for (int k = 0; k < 14; ++k) {
            float4 q = p[k];
            ab[2 * k]     = make_float2(q.x, q.y);
            ab[2 * k + 1] = make_float2(q.z, q.w);
        }
        float Sa = 0.0f, Sb = 0.0f;
#pragma unroll
        for (int j = 0; j < 21; ++j) { Sa += ab[j].x; Sb += ab[j].y; }
        *(float2*)&smem[REG2 + xb * HS_STRIDE + 2 * v] = make_float2(Sa, Sb);
#pragma unroll
        for (int t = 1; t < 8; ++t) {
            Sa += ab[t + 20].x - ab[t - 1].x;
            Sb += ab[t + 20].y - ab[t - 1].y;
            *(float2*)&smem[REG2 + (xb + t) * HS_STRIDE + 2 * v] = make_float2(Sa, Sb);
        }
    } else if (cornerBlk && tid == 255) {
        fixPy = (blockIdx.y == 0) ? 0 : (TILE - 1);
        fixPx = (blockIdx.x == 0) ? 0 : (TILE - 1);
        int degY = (blockIdx.y == 0) ? 0 : HALO;
        int degX = (blockIdx.x == 0) ? 0 : HALO;
        float pv = imc[(oy0 + fixPy) * HDIM + (ox0 + fixPx)];
        float aT = 1.0f / EPSF;
        float bT = pv * aT;
        asm volatile("" : "+v"(bT));
        float Sa = 0.0f, Sb = 0.0f;
#pragma unroll 1
        for (int dy = 0; dy < 21; ++dy) {
#pragma unroll 1
            for (int dx = 0; dx < 21; ++dx) {
                const float* c = &smem[(fixPy + dy) * AB_PITCH + 2 * (fixPx + dx)];
                float av = c[0], bv = c[1];
                if (dy == degY && dx == degX) { av = aT; bv = bT; }
                Sa = Sa + av;
                Sb = Sb + bv;
            }
        }
        float avga = Sa * INVF;
        float avgb = Sb * INVF;
        float tq = pv * avga;
        asm volatile("" : "+v"(tq));
        fixVal = tq - avgb;
    }
    __syncthreads();

    {
        int x = tid & 31, h = tid >> 5, y0 = 4 * h;
        const float2* p = (const float2*)&smem[REG2 + x * HS_STRIDE + 2 * y0];
        float2 vv[24];
#pragma unroll
        for (int j = 0; j < 24; ++j) vv[j] = p[j];
        float Sa = 0.0f, Sb = 0.0f;
#pragma unroll
        for (int j = 0; j < 21; ++j) { Sa += vv[j].x; Sb += vv[j].y; }
#pragma unroll
        for (int t = 0; t < 4; ++t) {
            if (t > 0) {
                Sa += vv[t + 20].x - vv[t - 1].x;
                Sb += vv[t + 20].y - vv[t - 1].y;
            }
            float avga = Sa * INVF, avgb = Sb * INVF;
            int oy = oy0 + y0 + t, ox = ox0 + x;
            float pix = imc[oy * HDIM + ox];
            oc[oy * HDIM + ox] = pix * avga - avgb;
        }
    }

    if (cornerBlk) {
        __syncthreads();
        if (tid == 255) oc[(oy0 + fixPy) * HDIM + (ox0 + fixPx)] = fixVal;
    }
}

extern "C" void kernel_launch(void* const* d_in, const int* in_sizes, int n_in,
                              void* d_out, int out_size, void* d_ws, size_t ws_size,
                              hipStream_t stream) {
    const float* img = (const float*)d_in[0];
    float* out = (float*)d_out;
    int nch = in_sizes[0] / (HDIM * HDIM);   // 16*3 = 48
    size_t need = (size_t)nch * ABW * ABP2 * sizeof(float2);   // ~404 MiB for 48 ch
    if (ws_size >= need) {
        float2* ab = (float2*)d_ws;
        dim3 g1(33, 33, nch);                 // 32x32 tiles over 1044^2
        san_k1<<<g1, dim3(256), 0, stream>>>(img, ab);
        dim3 g2(HDIM / TILE, HDIM / TILE, nch);
        san_k2<<<g2, dim3(256), 0, stream>>>(img, ab, out);
    } else {
        dim3 grid(HDIM / TILE, HDIM / TILE, nch);
        san_fused<<<grid, dim3(256), 0, stream>>>(img, out);
    }
}

// Round 12
// 444.672 us; speedup vs baseline: 1.9548x; 1.9548x over previous
//
#include <hip/hip_runtime.h>

#define HDIM 1024
#define TILE 32
#define HALO 20            // 2*PAD
#define MID  52            // TILE + HALO
#define ABW  1044          // (a,b) grid extent per side
#define ABP2 1056          // (a,b) plane row pitch in float2
#define EPSF 1e-8f
#define INVF ((float)(1.0 / 441.0))

// window-21 min/max scan: o[t] = (min,max) over v[t..t+20], t in [0,8), inputs v[0..27]
__device__ __forceinline__ void scan8_mm(const float* vm, const float* vx, float2* o) {
    float smn[8], smx[8];
    float amn = vm[20], amx = vx[20];
#pragma unroll
    for (int j = 19; j >= 8; --j) { amn = fminf(amn, vm[j]); amx = fmaxf(amx, vx[j]); }
#pragma unroll
    for (int i = 7; i >= 0; --i) {
        amn = fminf(amn, vm[i]); amx = fmaxf(amx, vx[i]);
        smn[i] = amn; smx[i] = amx;
    }
    float pmn = vm[21], pmx = vx[21];
    o[0] = make_float2(smn[0], smx[0]);
#pragma unroll
    for (int i = 1; i < 8; ++i) {
        o[i] = make_float2(fminf(smn[i], pmn), fmaxf(smx[i], pmx));
        if (i < 7) { pmn = fminf(pmn, vm[21 + i]); pmx = fmaxf(pmx, vx[21 + i]); }
    }
}

// ======================= K1: img -> (a,b) plane, 32x32 tiles, LDS overlay =======================
// Single 3776-word region (15.1 KB -> 8 blk/CU, thread-capped):
//   phase 1-2: img [52][54] = 2808 w ; phase 3-4: hmmT [32 cols][118] = 3776 w overlaid at 0
//   (h-scan results held in registers across the overlay barrier).
// hmmT row offset roff(j) = 2j + 2*(j>>3)  (pad every 8 rows: breaks the 32-word bank wrap).
#define K1_IMG_PITCH 54
#define K1_HMM_PITCH 118
#define K1_WORDS 3776

__global__ __launch_bounds__(256, 8) void san_k1(const float* __restrict__ img,
                                                 float2* __restrict__ ab) {
    __shared__ __align__(16) float smem[K1_WORDS];
    const int tid = threadIdx.x;
    const int I0 = blockIdx.x * TILE;
    const int J0 = blockIdx.y * TILE;
    const float* __restrict__ imc = img + (size_t)blockIdx.z * (HDIM * HDIM);
    float2* __restrict__ abc = ab + (size_t)blockIdx.z * ((size_t)ABW * ABP2);
    const bool xInt = (blockIdx.x > 0) && (blockIdx.x < gridDim.x - 1);

    // ---- phase 1: stage 52x52 replicate-clamped img patch (coalesced float2) ----
    for (int idx = tid; idx < 52 * 26; idx += 256) {
        int r = idx / 26, c2 = idx - r * 26;
        int gy = min(HDIM - 1, max(0, J0 - HALO + r));
        float2 t;
        if (xInt) {
            t = *(const float2*)(imc + gy * HDIM + (I0 - HALO) + 2 * c2);
        } else {
            int gx0 = min(HDIM - 1, max(0, I0 - HALO + 2 * c2));
            int gx1 = min(HDIM - 1, max(0, I0 - HALO + 2 * c2 + 1));
            t = make_float2(imc[gy * HDIM + gx0], imc[gy * HDIM + gx1]);
        }
        *(float2*)&smem[r * K1_IMG_PITCH + 2 * c2] = t;
    }
    __syncthreads();

    // ---- phase 2: h-minmax into REGISTERS. 52 rows x 4 groups of 8 = 208 lanes ----
    float2 ho[8];
    {
        int r = tid >> 2, g = tid & 3;
        if (tid < 208) {
            const float2* p = (const float2*)&smem[r * K1_IMG_PITCH + 8 * g];
            float v[28];
#pragma unroll
            for (int k = 0; k < 14; ++k) { float2 t = p[k]; v[2 * k] = t.x; v[2 * k + 1] = t.y; }
            scan8_mm(v, v, ho);
        }
    }
    __syncthreads();   // img region dead -> overlay hmmT

    // ---- phase 3: write transposed h-minmax over dead img region ----
    if (tid < 208) {
        int r = tid >> 2, g = tid & 3;
        int rw = 2 * r + 2 * (r >> 3);   // padded row offset
#pragma unroll
        for (int t = 0; t < 8; ++t)
            *(float2*)&smem[(8 * g + t) * K1_HMM_PITCH + rw] = ho[t];
    }
    __syncthreads();

    // ---- phase 4: v-minmax + (a,b) + global store. 32 cols x 4 groups of 8 = 128 lanes ----
    if (tid < 128) {
        int i = tid & 31, gj = tid >> 5;
        const float* base = &smem[i * K1_HMM_PITCH + 18 * gj];
        float vm[28], vx[28];
#pragma unroll
        for (int k = 0; k < 28; ++k) {
            float2 t = *(const float2*)(base + 2 * k + 2 * (k >> 3));
            vm[k] = t.x; vx[k] = t.y;
        }
        float2 o[8];
        scan8_mm(vm, vx, o);
#pragma unroll
        for (int t = 0; t < 8; ++t) {
            int jj = J0 + 8 * gj + t, ii = I0 + i;
            float mn = o[t].x, d = o[t].y - o[t].x;
            float a, b;
            if (d == 0.0f) {      // degenerate corner Q-point: clamp (consumer fixed up in K2)
                a = 1.0f; b = 0.0f;
            } else {
                a = 1.0f / (d + EPSF);
                b = mn * a;
            }
            if (jj < ABW && ii < ABW)
                abc[(size_t)jj * ABP2 + ii] = make_float2(a, b);
        }
    }
}

// ======================= K2: box-filter + combine, 32x32 tiles (proven R9) =======================
#define K2_AB_PITCH 108
#define K2_HS_PITCH 106
#define K2_WORDS 5620

__global__ __launch_bounds__(256, 7) void san_k2(const float* __restrict__ img,
                                                 const float2* __restrict__ ab,
                                                 float* __restrict__ out) {
    __shared__ __align__(16) float smem[K2_WORDS];
    const int tid = threadIdx.x;
    const int I0 = blockIdx.x * TILE;
    const int J0 = blockIdx.y * TILE;
    const float* __restrict__ imc = img + (size_t)blockIdx.z * (HDIM * HDIM);
    const float2* __restrict__ abc = ab + (size_t)blockIdx.z * ((size_t)ABW * ABP2);
    float* __restrict__ oc = out + (size_t)blockIdx.z * (HDIM * HDIM);

    // ---- prefetch this thread's 4 output pixels (used in phase 4) ----
    const int px_x = I0 + (tid & 31);
    const int px_y0 = J0 + 4 * (tid >> 5);
    float pix[4];
#pragma unroll
    for (int t = 0; t < 4; ++t) pix[t] = imc[(px_y0 + t) * HDIM + px_x];

    // ---- phase 1: stage ab tile rows J0..J0+51, 52 float2 (=26 float4) per row ----
    for (int idx = tid; idx < 52 * 26; idx += 256) {
        int r = idx / 26, c4 = idx - r * 26;
        const float4* gp = (const float4*)(abc + (size_t)(J0 + r) * ABP2 + I0) + c4;
        *(float4*)&smem[r * K2_AB_PITCH + 4 * c4] = *gp;
    }
    __syncthreads();

    // ---- phase 2: h sliding sums into REGISTERS (52 rows x 4 groups of 8 = 208 lanes);
    //      corner fixup on lane 255 (reads ab region, must finish before overlay) ----
    const bool cornerBlk = (blockIdx.x == 0 || blockIdx.x == gridDim.x - 1) &&
                           (blockIdx.y == 0 || blockIdx.y == gridDim.y - 1);
    float fixVal = 0.0f;
    int fixPy = 0, fixPx = 0;
    float hsa[8], hsb[8];
    if (tid < 208) {
        int v = tid >> 2, g = tid & 3;
        const float4* p = (const float4*)&smem[v * K2_AB_PITCH + 16 * g];
        float2 abv[28];
#pragma unroll
        for (int k = 0; k < 14; ++k) {
            float4 q = p[k];
            abv[2 * k]     = make_float2(q.x, q.y);
            abv[2 * k + 1] = make_float2(q.z, q.w);
        }
        float Sa = 0.0f, Sb = 0.0f;
#pragma unroll
        for (int j = 0; j < 21; ++j) { Sa += abv[j].x; Sb += abv[j].y; }
        hsa[0] = Sa; hsb[0] = Sb;
#pragma unroll
        for (int t = 1; t < 8; ++t) {
            Sa += abv[t + 20].x - abv[t - 1].x;
            Sb += abv[t + 20].y - abv[t - 1].y;
            hsa[t] = Sa; hsb[t] = Sb;
        }
    } else if (cornerBlk && tid == 255) {
        // bit-exact f32 replica of reference row-major sequential sums for the corner pixel
        fixPy = (blockIdx.y == 0) ? 0 : (TILE - 1);
        fixPx = (blockIdx.x == 0) ? 0 : (TILE - 1);
        int degY = (blockIdx.y == 0) ? 0 : HALO;
        int degX = (blockIdx.x == 0) ? 0 : HALO;
        float pv = imc[(J0 + fixPy) * HDIM + (I0 + fixPx)];
        float aT = 1.0f / EPSF;          // true a at degenerate point
        float bT = pv * aT;              // true b (single rounded f32 mul)
        asm volatile("" : "+v"(bT));     // forbid fma contraction
        float Sa = 0.0f, Sb = 0.0f;
#pragma unroll 1
        for (int dy = 0; dy < 21; ++dy) {
#pragma unroll 1
            for (int dx = 0; dx < 21; ++dx) {
                const float* c = &smem[(fixPy + dy) * K2_AB_PITCH + 2 * (fixPx + dx)];
                float av = c[0], bv = c[1];
                if (dy == degY && dx == degX) { av = aT; bv = bT; }
                Sa = Sa + av;
                Sb = Sb + bv;
            }
        }
        float avga = Sa * INVF;
        float avgb = Sb * INVF;
        float tq = pv * avga;
        asm volatile("" : "+v"(tq));     // mul then sub, like materialized ref
        fixVal = tq - avgb;
    }
    __syncthreads();   // all ab reads done -> safe to overlay hsT

    // ---- phase 3: write transposed h-sums over the dead ab region ----
    if (tid < 208) {
        int v = tid >> 2, g = tid & 3;
        int xp = 9 * g;   // group-padded transposed column index
#pragma unroll
        for (int t = 0; t < 8; ++t)
            *(float2*)&smem[(xp + t) * K2_HS_PITCH + 2 * v] = make_float2(hsa[t], hsb[t]);
    }
    __syncthreads();

    // ---- phase 4: v sliding sums + combine + store: 32 cols x 8 groups of 4 = 256 ----
    {
        int x = tid & 31, h = tid >> 5, y0 = 4 * h;
        int xp = 9 * (x >> 3) + (x & 7);
        const float2* p = (const float2*)&smem[xp * K2_HS_PITCH] + y0;
        float2 vv[24];
#pragma unroll
        for (int j = 0; j < 24; ++j) vv[j] = p[j];
        float Sa = 0.0f, Sb = 0.0f;
#pragma unroll
        for (int j = 0; j < 21; ++j) { Sa += vv[j].x; Sb += vv[j].y; }
#pragma unroll
        for (int t = 0; t < 4; ++t) {
            if (t > 0) {
                Sa += vv[t + 20].x - vv[t - 1].x;
                Sb += vv[t + 20].y - vv[t - 1].y;
            }
            float avga = Sa * INVF, avgb = Sb * INVF;
            oc[(px_y0 + t) * HDIM + px_x] = pix[t] * avga - avgb;
        }
    }

    if (cornerBlk) {
        __syncthreads();
        if (tid == 255) oc[(J0 + fixPy) * HDIM + (I0 + fixPx)] = fixVal;
    }
}

// ======================= fused fallback (R4, proven) =======================
#define IMG_PITCH 74
#define REG2 5616
#define HMM_STRIDE 148
#define AB_PITCH 108
#define HS_STRIDE 106
#define SMEM_WORDS 13328

__device__ __forceinline__ void scan14_mm(const float* vm, const float* vx, float2* o) {
    float smn[14], smx[14];
    float amn = vm[20], amx = vx[20];
#pragma unroll
    for (int j = 19; j >= 14; --j) { amn = fminf(amn, vm[j]); amx = fmaxf(amx, vx[j]); }
#pragma unroll
    for (int i = 13; i >= 0; --i) {
        amn = fminf(amn, vm[i]); amx = fmaxf(amx, vx[i]);
        smn[i] = amn; smx[i] = amx;
    }
    float pmn = vm[21], pmx = vx[21];
    o[0] = make_float2(smn[0], smx[0]);
#pragma unroll
    for (int i = 1; i < 14; ++i) {
        o[i] = make_float2(fminf(smn[i], pmn), fmaxf(smx[i], pmx));
        if (i < 13) { pmn = fminf(pmn, vm[21 + i]); pmx = fmaxf(pmx, vx[21 + i]); }
    }
}

__global__ __launch_bounds__(256, 3) void san_fused(const float* __restrict__ img,
                                                    float* __restrict__ out) {
    __shared__ __align__(16) float smem[SMEM_WORDS];
    const int tid = threadIdx.x;
    const int ox0 = blockIdx.x * TILE;
    const int oy0 = blockIdx.y * TILE;
    const float* __restrict__ imc = img + (size_t)blockIdx.z * (HDIM * HDIM);
    float* __restrict__ oc = out + (size_t)blockIdx.z * (HDIM * HDIM);
    const bool xInterior = (blockIdx.x > 0) && (blockIdx.x < gridDim.x - 1);

    for (int idx = tid; idx < 72 * 36; idx += 256) {
        int r = idx / 36, c2 = idx - r * 36;
        int gy = min(HDIM - 1, max(0, oy0 - HALO + r));
        float2 t;
        if (xInterior) {
            t = *(const float2*)(imc + gy * HDIM + (ox0 - HALO) + 2 * c2);
        } else {
            int gx0 = min(HDIM - 1, max(0, ox0 - HALO + 2 * c2));
            int gx1 = min(HDIM - 1, max(0, ox0 - HALO + 2 * c2 + 1));
            t = make_float2(imc[gy * HDIM + gx0], imc[gy * HDIM + gx1]);
        }
        *(float2*)&smem[r * IMG_PITCH + 2 * c2] = t;
    }
    __syncthreads();

    for (int task = tid; task < 288; task += 256) {
        int r = task >> 2, g = task & 3, u0 = 14 * g;
        const float2* p = (const float2*)&smem[r * IMG_PITCH + u0];
        float v[34];
#pragma unroll
        for (int k = 0; k < 17; ++k) { float2 t = p[k]; v[2 * k] = t.x; v[2 * k + 1] = t.y; }
        float2 o[14];
        scan14_mm(v, v, o);
#pragma unroll
        for (int i = 0; i < 14; ++i) {
            int u = u0 + i;
            if (u < MID) *(float2*)&smem[REG2 + u * HMM_STRIDE + 2 * r] = o[i];
        }
    }
    __syncthreads();

    if (tid < 208) {
        int u = tid % MID, v0 = 14 * (tid / MID);
        const float4* p = (const float4*)&smem[REG2 + u * HMM_STRIDE + 2 * v0];
        float vm[34], vx[34];
#pragma unroll
        for (int k = 0; k < 17; ++k) {
            float4 q = p[k];
            vm[2 * k] = q.x; vx[2 * k] = q.y; vm[2 * k + 1] = q.z; vx[2 * k + 1] = q.w;
        }
        float2 o[14];
        scan14_mm(vm, vx, o);
#pragma unroll
        for (int i = 0; i < 14; ++i) {
            int v = v0 + i;
            if (v < MID) {
                float mn = o[i].x, d = o[i].y - o[i].x;
                float a, b;
                if (d == 0.0f) { a = 1.0f; b = 0.0f; }
                else { a = 1.0f / (d + EPSF); b = mn * a; }
                *(float2*)&smem[v * AB_PITCH + 2 * u] = make_float2(a, b);
            }
        }
    }
    __syncthreads();

    const bool cornerBlk = (blockIdx.x == 0 || blockIdx.x == gridDim.x - 1) &&
                           (blockIdx.y == 0 || blockIdx.y == gridDim.y - 1);
    float fixVal = 0.0f;
    int fixPy = 0, fixPx = 0;
    if (tid < 208) {
        int v = tid >> 2, g = tid & 3, xb = 8 * g;
        const float4* p = (const float4*)&smem[v * AB_PITCH + 16 * g];
        float2 ab[28];
#pragma unroll
        for (int k = 0; k < 14; ++k) {
            float4 q = p[k];
            ab[2 * k]     = make_float2(q.x, q.y);
            ab[2 * k + 1] = make_float2(q.z, q.w);
        }
        float Sa = 0.0f, Sb = 0.0f;
#pragma unroll
        for (int j = 0; j < 21; ++j) { Sa += ab[j].x; Sb += ab[j].y; }
        *(float2*)&smem[REG2 + xb * HS_STRIDE + 2 * v] = make_float2(Sa, Sb);
#pragma unroll
        for (int t = 1; t < 8; ++t) {
            Sa += ab[t + 20].x - ab[t - 1].x;
            Sb += ab[t + 20].y - ab[t - 1].y;
            *(float2*)&smem[REG2 + (xb + t) * HS_STRIDE + 2 * v] = make_float2(Sa, Sb);
        }
    } else if (cornerBlk && tid == 255) {
        fixPy = (blockIdx.y == 0) ? 0 : (TILE - 1);
        fixPx = (blockIdx.x == 0) ? 0 : (TILE - 1);
        int degY = (blockIdx.y == 0) ? 0 : HALO;
        int degX = (blockIdx.x == 0) ? 0 : HALO;
        float pv = imc[(oy0 + fixPy) * HDIM + (ox0 + fixPx)];
        float aT = 1.0f / EPSF;
        float bT = pv * aT;
        asm volatile("" : "+v"(bT));
        float Sa = 0.0f, Sb = 0.0f;
#pragma unroll 1
        for (int dy = 0; dy < 21; ++dy) {
#pragma unroll 1
            for (int dx = 0; dx < 21; ++dx) {
                const float* c = &smem[(fixPy + dy) * AB_PITCH + 2 * (fixPx + dx)];
                float av = c[0], bv = c[1];
                if (dy == degY && dx == degX) { av = aT; bv = bT; }
                Sa = Sa + av;
                Sb = Sb + bv;
            }
        }
        float avga = Sa * INVF;
        float avgb = Sb * INVF;
        float tq = pv * avga;
        asm volatile("" : "+v"(tq));
        fixVal = tq - avgb;
    }
    __syncthreads();

    {
        int x = tid & 31, h = tid >> 5, y0 = 4 * h;
        const float2* p = (const float2*)&smem[REG2 + x * HS_STRIDE + 2 * y0];
        float2 vv[24];
#pragma unroll
        for (int j = 0; j < 24; ++j) vv[j] = p[j];
        float Sa = 0.0f, Sb = 0.0f;
#pragma unroll
        for (int j = 0; j < 21; ++j) { Sa += vv[j].x; Sb += vv[j].y; }
#pragma unroll
        for (int t = 0; t < 4; ++t) {
            if (t > 0) {
                Sa += vv[t + 20].x - vv[t - 1].x;
                Sb += vv[t + 20].y - vv[t - 1].y;
            }
            float avga = Sa * INVF, avgb = Sb * INVF;
            int oy = oy0 + y0 + t, ox = ox0 + x;
            float pix = imc[oy * HDIM + ox];
            oc[oy * HDIM + ox] = pix * avga - avgb;
        }
    }

    if (cornerBlk) {
        __syncthreads();
        if (tid == 255) oc[(oy0 + fixPy) * HDIM + (ox0 + fixPx)] = fixVal;
    }
}

extern "C" void kernel_launch(void* const* d_in, const int* in_sizes, int n_in,
                              void* d_out, int out_size, void* d_ws, size_t ws_size,
                              hipStream_t stream) {
    const float* img = (const float*)d_in[0];
    float* out = (float*)d_out;
    int nch = in_sizes[0] / (HDIM * HDIM);   // 16*3 = 48
    size_t need = (size_t)nch * ABW * ABP2 * sizeof(float2);   // ~404 MiB for 48 ch
    if (ws_size >= need) {
        float2* ab = (float2*)d_ws;
        dim3 g1(33, 33, nch);                 // 32x32 tiles over 1044^2
        san_k1<<<g1, dim3(256), 0, stream>>>(img, ab);
        dim3 g2(HDIM / TILE, HDIM / TILE, nch);
        san_k2<<<g2, dim3(256), 0, stream>>>(img, ab, out);
    } else {
        dim3 grid(HDIM / TILE, HDIM / TILE, nch);
        san_fused<<<grid, dim3(256), 0, stream>>>(img, out);
    }
}